// Round 4
// baseline (341.625 us; speedup 1.0000x reference)
//
#include <hip/hip_runtime.h>

#define BATCH   262144
#define IN_DIM  28
#define HID     128
#define LAT     64
#define NCODES  512
#define NBLK    (BATCH / 64)
#define NWAVE   (NBLK * 4)

typedef short v8s __attribute__((ext_vector_type(8)));
typedef float v4f __attribute__((ext_vector_type(4)));

__device__ __forceinline__ unsigned short f2bf(float f) {
  unsigned u = __float_as_uint(f);
  u += 0x7fffu + ((u >> 16) & 1u);   // round-to-nearest-even
  return (unsigned short)(u >> 16);
}

// XOR-swizzled 16-row LDS tile, 16B-block granular: col group g = col>>3,
// block index = g*16 + (row ^ g), element = col&7. Unique, zero padding,
// ds_read_b128 of a row-fragment is bank-uniform (8-cyc floor), scalar b16
// writes are <=4-way. Offset in shorts.
__device__ __forceinline__ int swz(int row, int col) {
  int g = col >> 3;
  return (g * 16 + ((row ^ g) & 15)) * 8 + (col & 7);
}

// ---------------- prep: bf16 fragment-layout weights into ws ----------------
// w1t [128][32] enc_w1^T (k>=28 zero) | w2t [64][128] enc_w2^T
// cbt [512][64] bf16 codebook | cbtm2 [512][64] bf16(-2*codebook) (exact)
// dw1t [128][64] dec_w1^T | dw2t [32][128] dec_w2^T (n>=28 zero) | e2 [512] fp32
__global__ __launch_bounds__(256) void vq_prep(
    const float* __restrict__ ew1, const float* __restrict__ ew2,
    const float* __restrict__ cb,  const float* __restrict__ dw1,
    const float* __restrict__ dw2,
    unsigned short* __restrict__ w1t, unsigned short* __restrict__ w2t,
    unsigned short* __restrict__ cbt, unsigned short* __restrict__ cbtm2,
    unsigned short* __restrict__ dw1t, unsigned short* __restrict__ dw2t,
    float* __restrict__ e2) {
  int i = blockIdx.x * 256 + threadIdx.x;
  if (i < 4096) {
    int n = i >> 5, k = i & 31;
    w1t[i] = (k < IN_DIM) ? f2bf(ew1[k * HID + n]) : (unsigned short)0;
  } else if (i < 12288) {
    int j = i - 4096; int n = j >> 7, k = j & 127;
    w2t[j] = f2bf(ew2[k * LAT + n]);
  } else if (i < 45056) {
    int j = i - 12288;
    cbt[j] = f2bf(cb[j]);
  } else if (i < 77824) {
    int j = i - 45056;
    cbtm2[j] = f2bf(-2.0f * cb[j]);
  } else if (i < 86016) {
    int j = i - 77824; int n = j >> 6, k = j & 63;
    dw1t[j] = f2bf(dw1[k * HID + n]);
  } else if (i < 90112) {
    int j = i - 86016; int n = j >> 7, k = j & 127;
    dw2t[j] = (n < IN_DIM) ? f2bf(dw2[k * IN_DIM + n]) : (unsigned short)0;
  } else if (i < 90624) {
    int c = i - 90112;
    float s = 0.f;
    for (int d = 0; d < LAT; ++d) { float v = cb[c * LAT + d]; s += v * v; }
    e2[c] = s;
  }
}

// ---------------- fused main kernel ----------------
// 4 waves/block, 16 rows/wave, swizzled per-wave 4 KB LDS tile reused
// H -> Z -> HD (in-order per-wave DS, no barriers). LDS = 16384 exactly ->
// 4 blocks/CU with __launch_bounds__(256,4) (VGPR cap 128). Biases and e2
// folded into MFMA acc-init; argmin uses cbtm2 = -2*cb so the loop is pure
// load->MFMA->compare; vq loss = z^2 + bestd (no codebook gather).
__global__ __launch_bounds__(256, 4) void vq_main(
    const float* __restrict__ x,
    const float* __restrict__ b1, const float* __restrict__ b2,
    const float* __restrict__ db1, const float* __restrict__ db2,
    const unsigned short* __restrict__ w1t, const unsigned short* __restrict__ w2t,
    const unsigned short* __restrict__ cbt, const unsigned short* __restrict__ cbtm2,
    const unsigned short* __restrict__ dw1t, const unsigned short* __restrict__ dw2t,
    const float* __restrict__ e2,
    float* __restrict__ out, float* __restrict__ partials) {

  __shared__ __align__(16) unsigned short buf[4][2048];   // 16384 B exactly

  const int tid  = threadIdx.x;
  const int wave = tid >> 6;
  const int lane = tid & 63;
  const int quad = lane >> 4;
  const int lm   = lane & 15;
  const int r0   = blockIdx.x * 64 + wave * 16;

  unsigned short* W = &buf[wave][0];

  // ---- stage 1: H = relu(X @ W1 + b1), bias in acc-init ----
  v8s a1;
  {
    const float* xp = x + (size_t)(r0 + lm) * IN_DIM + quad * 8;
    float4 v0 = *(const float4*)xp;
    float4 v1;
    if (quad == 3) { v1.x = 0.f; v1.y = 0.f; v1.z = 0.f; v1.w = 0.f; }
    else           { v1 = *(const float4*)(xp + 4); }
    a1[0] = (short)f2bf(v0.x); a1[1] = (short)f2bf(v0.y);
    a1[2] = (short)f2bf(v0.z); a1[3] = (short)f2bf(v0.w);
    a1[4] = (short)f2bf(v1.x); a1[5] = (short)f2bf(v1.y);
    a1[6] = (short)f2bf(v1.z); a1[7] = (short)f2bf(v1.w);
  }
  {
    v4f acc[8];
#pragma unroll
    for (int nt = 0; nt < 8; ++nt) {
      float bv = b1[nt * 16 + lm];
      v4f ci = {bv, bv, bv, bv};
      v8s b = *(const v8s*)(w1t + (nt * 16 + lm) * 32 + quad * 8);
      acc[nt] = __builtin_amdgcn_mfma_f32_16x16x32_bf16(a1, b, ci, 0, 0, 0);
    }
#pragma unroll
    for (int nt = 0; nt < 8; ++nt) {
#pragma unroll
      for (int r = 0; r < 4; ++r) {
        float h = fmaxf(acc[nt][r], 0.f);
        W[swz(quad * 4 + r, nt * 16 + lm)] = f2bf(h);
      }
    }
  }

  // ---- stage 2: Z = H @ W2 + b2 (z fp32 in regs) ----
  v4f accz[4];
  {
    v8s ha[4];
#pragma unroll
    for (int ks = 0; ks < 4; ++ks)
      ha[ks] = *(const v8s*)&W[swz(lm, ks * 32 + quad * 8)];
#pragma unroll
    for (int nt = 0; nt < 4; ++nt) {
      float bv = b2[nt * 16 + lm];
      accz[nt] = (v4f){bv, bv, bv, bv};
#pragma unroll
      for (int ks = 0; ks < 4; ++ks) {
        v8s b = *(const v8s*)(w2t + (nt * 16 + lm) * 128 + ks * 32 + quad * 8);
        accz[nt] = __builtin_amdgcn_mfma_f32_16x16x32_bf16(ha[ks], b, accz[nt], 0, 0, 0);
      }
    }
#pragma unroll
    for (int nt = 0; nt < 4; ++nt)
#pragma unroll
      for (int r = 0; r < 4; ++r)
        W[swz(quad * 4 + r, nt * 16 + lm)] = f2bf(accz[nt][r]);
  }

  // ---- stage 3: dist = e2 - 2 z.e via cbtm2, e2 in acc-init; argmin ----
  float bd0[4], bd1[4]; int bc0[4], bc1[4];
#pragma unroll
  for (int r = 0; r < 4; ++r) {
    bd0[r] = 3.4e38f; bc0[r] = 0x7fffffff;
    bd1[r] = 3.4e38f; bc1[r] = 0x7fffffff;
  }
  {
    v8s za0 = *(const v8s*)&W[swz(lm, quad * 8)];
    v8s za1 = *(const v8s*)&W[swz(lm, 32 + quad * 8)];
#pragma unroll 4
    for (int nt = 0; nt < 16; ++nt) {
      int c0 = nt * 16 + lm;
      int c1 = c0 + 256;
      v8s p0 = *(const v8s*)(cbtm2 + c0 * 64 + quad * 8);
      v8s p1 = *(const v8s*)(cbtm2 + c0 * 64 + 32 + quad * 8);
      v8s q0 = *(const v8s*)(cbtm2 + c1 * 64 + quad * 8);
      v8s q1 = *(const v8s*)(cbtm2 + c1 * 64 + 32 + quad * 8);
      float eA = e2[c0], eB = e2[c1];
      v4f cA = {eA, eA, eA, eA};
      v4f cB = {eB, eB, eB, eB};
      v4f accA = __builtin_amdgcn_mfma_f32_16x16x32_bf16(za0, p0, cA, 0, 0, 0);
      accA = __builtin_amdgcn_mfma_f32_16x16x32_bf16(za1, p1, accA, 0, 0, 0);
      v4f accB = __builtin_amdgcn_mfma_f32_16x16x32_bf16(za0, q0, cB, 0, 0, 0);
      accB = __builtin_amdgcn_mfma_f32_16x16x32_bf16(za1, q1, accB, 0, 0, 0);
#pragma unroll
      for (int r = 0; r < 4; ++r) {
        if (accA[r] < bd0[r]) { bd0[r] = accA[r]; bc0[r] = c0; }
        if (accB[r] < bd1[r]) { bd1[r] = accB[r]; bc1[r] = c1; }
      }
    }
  }
  float bestd[4]; int bestc[4]; float z2p[4];
#pragma unroll
  for (int r = 0; r < 4; ++r) {
    bestd[r] = bd0[r]; bestc[r] = bc0[r];
    if (bd1[r] < bestd[r]) { bestd[r] = bd1[r]; bestc[r] = bc1[r]; }
    z2p[r] = accz[0][r] * accz[0][r] + accz[1][r] * accz[1][r]
           + accz[2][r] * accz[2][r] + accz[3][r] * accz[3][r];
  }
  // 16-lane reduce per quad-group: argmin (with index tie-break) + z^2 sum
#pragma unroll
  for (int off = 1; off < 16; off <<= 1) {
#pragma unroll
    for (int r = 0; r < 4; ++r) {
      float od = __shfl_xor(bestd[r], off, 64);
      int   oc = __shfl_xor(bestc[r], off, 64);
      if (od < bestd[r] || (od == bestd[r] && oc < bestc[r])) { bestd[r] = od; bestc[r] = oc; }
      z2p[r] += __shfl_xor(z2p[r], off, 64);
    }
  }
  // vq partial: ||z-q||^2 = z^2 + (e^2 - 2 z.e) = z2p + bestd, once per quad
  float vqacc = 0.f;
  if (lm == 0) {
#pragma unroll
    for (int r = 0; r < 4; ++r) vqacc += z2p[r] + bestd[r];
  }

  // broadcast idx[m] so every lane knows the code for row m = lm
  int i0 = __shfl(bestc[0], (lm >> 2) << 4, 64);
  int i1 = __shfl(bestc[1], (lm >> 2) << 4, 64);
  int i2 = __shfl(bestc[2], (lm >> 2) << 4, 64);
  int i3 = __shfl(bestc[3], (lm >> 2) << 4, 64);
  int sel = lm & 3;
  int idxv = sel == 0 ? i0 : sel == 1 ? i1 : sel == 2 ? i2 : i3;

  // ---- stage 5: HD = relu(Q @ DW1 + db1) ----
  {
    v8s qa0 = *(const v8s*)(cbt + (size_t)idxv * 64 + quad * 8);
    v8s qa1 = *(const v8s*)(cbt + (size_t)idxv * 64 + 32 + quad * 8);
    v4f acc[8];
#pragma unroll
    for (int nt = 0; nt < 8; ++nt) {
      float bv = db1[nt * 16 + lm];
      acc[nt] = (v4f){bv, bv, bv, bv};
      v8s b0  = *(const v8s*)(dw1t + (nt * 16 + lm) * 64 + quad * 8);
      v8s b1v = *(const v8s*)(dw1t + (nt * 16 + lm) * 64 + 32 + quad * 8);
      acc[nt] = __builtin_amdgcn_mfma_f32_16x16x32_bf16(qa0, b0, acc[nt], 0, 0, 0);
      acc[nt] = __builtin_amdgcn_mfma_f32_16x16x32_bf16(qa1, b1v, acc[nt], 0, 0, 0);
    }
#pragma unroll
    for (int nt = 0; nt < 8; ++nt)
#pragma unroll
      for (int r = 0; r < 4; ++r) {
        float h = fmaxf(acc[nt][r], 0.f);
        W[swz(quad * 4 + r, nt * 16 + lm)] = f2bf(h);
      }
  }

  // ---- stage 6: R = HD @ DW2 + db2; store + recon loss ----
  float racc = 0.f;
  {
    v8s hd[4];
#pragma unroll
    for (int ks = 0; ks < 4; ++ks)
      hd[ks] = *(const v8s*)&W[swz(lm, ks * 32 + quad * 8)];
    v4f acc[2];
#pragma unroll
    for (int nt = 0; nt < 2; ++nt) {
      int n = nt * 16 + lm;
      float bv = (n < IN_DIM) ? db2[n] : 0.f;
      acc[nt] = (v4f){bv, bv, bv, bv};
#pragma unroll
      for (int ks = 0; ks < 4; ++ks) {
        v8s b = *(const v8s*)(dw2t + (nt * 16 + lm) * 128 + ks * 32 + quad * 8);
        acc[nt] = __builtin_amdgcn_mfma_f32_16x16x32_bf16(hd[ks], b, acc[nt], 0, 0, 0);
      }
    }
#pragma unroll
    for (int nt = 0; nt < 2; ++nt) {
      int n = nt * 16 + lm;
      bool valid = (n < IN_DIM);
#pragma unroll
      for (int r = 0; r < 4; ++r) {
        int m = quad * 4 + r;
        float rec = acc[nt][r];
        if (valid) {
          size_t o = (size_t)(r0 + m) * IN_DIM + n;
          out[o] = rec;
          float dv = rec - x[o];
          racc += dv * dv;
        }
      }
    }
  }

  // ---- per-wave butterfly, direct per-wave partial store (no barriers) ----
#pragma unroll
  for (int off = 1; off < 64; off <<= 1) {
    racc  += __shfl_xor(racc, off, 64);
    vqacc += __shfl_xor(vqacc, off, 64);
  }
  if (lane == 0) {
    size_t w = (size_t)blockIdx.x * 4 + wave;
    partials[w * 2]     = racc;
    partials[w * 2 + 1] = vqacc;
  }
}

// ---------------- finalize: reduce per-wave partials, write scalars ----------------
__global__ __launch_bounds__(256) void vq_fin(const float* __restrict__ partials,
                                              float* __restrict__ out) {
  float r = 0.f, v = 0.f;
  for (int i = threadIdx.x; i < NWAVE; i += 256) {
    r += partials[2 * i];
    v += partials[2 * i + 1];
  }
#pragma unroll
  for (int off = 1; off < 64; off <<= 1) {
    r += __shfl_xor(r, off, 64);
    v += __shfl_xor(v, off, 64);
  }
  __shared__ float s[4][2];
  int w = threadIdx.x >> 6;
  if ((threadIdx.x & 63) == 0) { s[w][0] = r; s[w][1] = v; }
  __syncthreads();
  if (threadIdx.x == 0) {
    float R = s[0][0] + s[1][0] + s[2][0] + s[3][0];
    float V = s[0][1] + s[1][1] + s[2][1] + s[3][1];
    out[7340032] = R * (1.0f / 7340032.0f);          // recon_loss = S / (B*28)
    out[7340033] = V * (1.25f / 16777216.0f);        // vq_loss = 1.25 * S / (B*64)
  }
}

extern "C" void kernel_launch(void* const* d_in, const int* in_sizes, int n_in,
                              void* d_out, int out_size, void* d_ws, size_t ws_size,
                              hipStream_t stream) {
  const float* x   = (const float*)d_in[0];
  const float* ew1 = (const float*)d_in[1];
  const float* eb1 = (const float*)d_in[2];
  const float* ew2 = (const float*)d_in[3];
  const float* eb2 = (const float*)d_in[4];
  const float* cb  = (const float*)d_in[5];
  const float* dw1 = (const float*)d_in[6];
  const float* db1 = (const float*)d_in[7];
  const float* dw2 = (const float*)d_in[8];
  const float* db2 = (const float*)d_in[9];

  char* ws = (char*)d_ws;
  unsigned short* w1t   = (unsigned short*)(ws + 0);        //   8192 B
  unsigned short* w2t   = (unsigned short*)(ws + 8192);     //  16384 B
  unsigned short* cbt   = (unsigned short*)(ws + 24576);    //  65536 B
  unsigned short* cbtm2 = (unsigned short*)(ws + 90112);    //  65536 B
  unsigned short* dw1t  = (unsigned short*)(ws + 155648);   //  16384 B
  unsigned short* dw2t  = (unsigned short*)(ws + 172032);   //   8192 B
  float* e2       = (float*)(ws + 180224);                  //   2048 B
  float* partials = (float*)(ws + 182272);                  // 131072 B

  float* out = (float*)d_out;

  vq_prep<<<354, 256, 0, stream>>>(ew1, ew2, cb, dw1, dw2,
                                   w1t, w2t, cbt, cbtm2, dw1t, dw2t, e2);
  vq_main<<<NBLK, 256, 0, stream>>>(x, eb1, eb2, db1, db2,
                                    w1t, w2t, cbt, cbtm2, dw1t, dw2t, e2,
                                    out, partials);
  vq_fin<<<1, 256, 0, stream>>>(partials, out);
}

// Round 5
// 207.062 us; speedup vs baseline: 1.6499x; 1.6499x over previous
//
#include <hip/hip_runtime.h>

#define BATCH   262144
#define IN_DIM  28
#define HID     128
#define LAT     64
#define NCODES  512
#define NBLK    1024            // 256 rows per block
#define NWAVE   (NBLK * 4)      // 64 rows per wave

#define BLOB_SHORTS 57344       // bf16 table region (shorts)
#define BLOB_F32    864         // fp32 region (e2 + biases)
#define BLOB_BYTES  (BLOB_SHORTS * 2 + BLOB_F32 * 4)   // 118144
#define ACT_BASE    (BLOB_BYTES / 2)                    // short offset 59072
#define LDS_BYTES   (BLOB_BYTES + 8 * 2048 * 2)         // 150912

typedef short v8s __attribute__((ext_vector_type(8)));
typedef float v4f __attribute__((ext_vector_type(4)));

__device__ __forceinline__ unsigned short f2bf(float f) {
  unsigned u = __float_as_uint(f);
  u += 0x7fffu + ((u >> 16) & 1u);   // round-to-nearest-even
  return (unsigned short)(u >> 16);
}

// Bank-swizzled table offset (in shorts): row-major with 16B col-blocks
// XOR-permuted by row so same-col-block reads across lanes hit distinct banks.
__device__ __forceinline__ int toff(int base, int row, int col, int SB) {
  return base + row * (SB * 8) + ((((col >> 3) ^ row) & (SB - 1)) << 3) + (col & 7);
}

// XOR-swizzled 16-row activation tile (per wave,t), offsets in shorts.
__device__ __forceinline__ int swz(int row, int col) {
  int g = col >> 3;
  return (g * 16 + ((row ^ g) & 15)) * 8 + (col & 7);
}

// Blob layout (short offsets):
//   lw1  @0      [128 n][32 k]  SB=4   enc_w1^T (k>=28 zero)
//   lw2  @4096   [64 n][128 k]  SB=16  enc_w2^T
//   lcb  @12288  [512 c][64 d]  SB=8   bf16 codebook
//   ld1  @45056  [128 n][64 k]  SB=8   dec_w1^T
//   ld2  @53248  [32 n][128 k]  SB=16  dec_w2^T (n>=28 zero)
// fp32 @ byte 114688: e2[512], b1[128], b2[64], db1[128], db2[32 pad0]
__global__ __launch_bounds__(256) void vq_prep(
    const float* __restrict__ ew1, const float* __restrict__ eb1,
    const float* __restrict__ ew2, const float* __restrict__ eb2,
    const float* __restrict__ cb,  const float* __restrict__ dw1,
    const float* __restrict__ db1, const float* __restrict__ dw2,
    const float* __restrict__ db2,
    unsigned short* __restrict__ blob) {
  int i = blockIdx.x * 256 + threadIdx.x;
  float* fb = (float*)(blob + BLOB_SHORTS);
  if (i < 4096) {                       // lw1
    int row = i >> 5, col = i & 31;
    float v = (col < IN_DIM) ? ew1[col * HID + row] : 0.f;
    blob[toff(0, row, col, 4)] = f2bf(v);
  } else if (i < 12288) {               // lw2
    int j = i - 4096; int row = j >> 7, col = j & 127;
    blob[toff(4096, row, col, 16)] = f2bf(ew2[col * LAT + row]);
  } else if (i < 45056) {               // lcb
    int j = i - 12288; int row = j >> 6, col = j & 63;
    blob[toff(12288, row, col, 8)] = f2bf(cb[j]);
  } else if (i < 53248) {               // ld1
    int j = i - 45056; int row = j >> 6, col = j & 63;
    blob[toff(45056, row, col, 8)] = f2bf(dw1[col * HID + row]);
  } else if (i < 57344) {               // ld2
    int j = i - 53248; int row = j >> 7, col = j & 127;
    float v = (row < IN_DIM) ? dw2[col * IN_DIM + row] : 0.f;
    blob[toff(53248, row, col, 16)] = f2bf(v);
  } else if (i < 57344 + 512) {         // e2
    int c = i - 57344;
    float s = 0.f;
    for (int d = 0; d < LAT; ++d) { float v = cb[c * LAT + d]; s += v * v; }
    fb[c] = s;
  } else if (i < 57344 + 640) {
    fb[i - 57344] = eb1[i - 57344 - 512];
  } else if (i < 57344 + 704) {
    fb[i - 57344] = eb2[i - 57344 - 640];
  } else if (i < 57344 + 832) {
    fb[i - 57344] = db1[i - 57344 - 704];
  } else if (i < 57344 + 864) {
    int k = i - 57344 - 832;
    fb[i - 57344] = (k < IN_DIM) ? db2[k] : 0.f;
  }
}

// ---------------- fused main kernel ----------------
// All tables staged in LDS once per block (kills the per-wave ~114 KB L2/L3
// table re-read that pinned rounds 3-4 at 253 us). Each wave: 64 rows as
// 2 groups of 2 row-tiles (R=2 for ILP + frag reuse). One barrier (staging).
__global__ __launch_bounds__(256, 1) void vq_main(
    const float* __restrict__ x,
    const unsigned short* __restrict__ blob,
    float* __restrict__ out, float* __restrict__ partials) {

  extern __shared__ __align__(16) char smem[];
  unsigned short* L  = (unsigned short*)smem;
  float*          LF = (float*)(smem + BLOB_SHORTS * 2);

  const int tid  = threadIdx.x;
  const int wave = tid >> 6;
  const int lane = tid & 63;
  const int quad = lane >> 4;
  const int lm   = lane & 15;

  // ---- stage tables into LDS (one-time) ----
  {
    const float4* src = (const float4*)blob;
    float4* dst = (float4*)smem;
#pragma unroll
    for (int it = 0; it < 29; ++it) {
      int idx = it * 256 + tid;
      if (idx < BLOB_BYTES / 16) dst[idx] = src[idx];
    }
  }
  __syncthreads();

  unsigned short* A0 = L + ACT_BASE + (wave * 2 + 0) * 2048;
  unsigned short* A1 = L + ACT_BASE + (wave * 2 + 1) * 2048;
  unsigned short* Act[2] = {A0, A1};

  float racc = 0.f, vqacc = 0.f;
  const int rbase = blockIdx.x * 256 + wave * 64;

#pragma unroll
  for (int g = 0; g < 2; ++g) {
    const int rt0 = rbase + g * 32;        // t=0 rows; t=1 adds 16

    // ---- stage 1: H = relu(X @ W1 + b1) ----
    v8s a1[2];
#pragma unroll
    for (int t = 0; t < 2; ++t) {
      const float* xp = x + (size_t)(rt0 + t * 16 + lm) * IN_DIM + quad * 8;
      float4 v0 = *(const float4*)xp;
      float4 v1;
      if (quad == 3) { v1.x = 0.f; v1.y = 0.f; v1.z = 0.f; v1.w = 0.f; }
      else           { v1 = *(const float4*)(xp + 4); }
      a1[t][0] = (short)f2bf(v0.x); a1[t][1] = (short)f2bf(v0.y);
      a1[t][2] = (short)f2bf(v0.z); a1[t][3] = (short)f2bf(v0.w);
      a1[t][4] = (short)f2bf(v1.x); a1[t][5] = (short)f2bf(v1.y);
      a1[t][6] = (short)f2bf(v1.z); a1[t][7] = (short)f2bf(v1.w);
    }
#pragma unroll
    for (int nt = 0; nt < 8; ++nt) {
      int row = nt * 16 + lm;
      v8s frag = *(const v8s*)&L[toff(0, row, quad * 8, 4)];
      float bv = LF[512 + row];
      v4f seed = {bv, bv, bv, bv};
#pragma unroll
      for (int t = 0; t < 2; ++t) {
        v4f acc = __builtin_amdgcn_mfma_f32_16x16x32_bf16(a1[t], frag, seed, 0, 0, 0);
#pragma unroll
        for (int r = 0; r < 4; ++r)
          Act[t][swz(quad * 4 + r, row)] = f2bf(fmaxf(acc[r], 0.f));
      }
    }

    // ---- stage 2: Z = H @ W2 + b2 (z fp32 in regs) ----
    v4f accz[2][4];
    {
      v8s ha[2][4];
#pragma unroll
      for (int t = 0; t < 2; ++t)
#pragma unroll
        for (int ks = 0; ks < 4; ++ks)
          ha[t][ks] = *(const v8s*)&Act[t][swz(lm, ks * 32 + quad * 8)];
#pragma unroll
      for (int nt = 0; nt < 4; ++nt) {
        int row = nt * 16 + lm;
        float bv = LF[640 + row];
#pragma unroll
        for (int t = 0; t < 2; ++t) accz[t][nt] = (v4f){bv, bv, bv, bv};
#pragma unroll
        for (int ks = 0; ks < 4; ++ks) {
          v8s frag = *(const v8s*)&L[toff(4096, row, ks * 32 + quad * 8, 16)];
#pragma unroll
          for (int t = 0; t < 2; ++t)
            accz[t][nt] = __builtin_amdgcn_mfma_f32_16x16x32_bf16(ha[t][ks], frag, accz[t][nt], 0, 0, 0);
        }
      }
      // write zm2 = bf16(-2*z) (exact x2) for the argmin MFMA A-operand
#pragma unroll
      for (int t = 0; t < 2; ++t)
#pragma unroll
        for (int nt = 0; nt < 4; ++nt)
#pragma unroll
          for (int r = 0; r < 4; ++r)
            Act[t][swz(quad * 4 + r, nt * 16 + lm)] = f2bf(-2.f * accz[t][nt][r]);
    }

    // ---- argmin: dist = e2 + (-2z).e via MFMA, e2 in acc seed ----
    float bd[2][4]; int bc[2][4];
#pragma unroll
    for (int t = 0; t < 2; ++t)
#pragma unroll
      for (int r = 0; r < 4; ++r) { bd[t][r] = 3.4e38f; bc[t][r] = 0x7fffffff; }
    {
      v8s za[2][2];
#pragma unroll
      for (int t = 0; t < 2; ++t) {
        za[t][0] = *(const v8s*)&Act[t][swz(lm, quad * 8)];
        za[t][1] = *(const v8s*)&Act[t][swz(lm, 32 + quad * 8)];
      }
#pragma unroll 4
      for (int ct = 0; ct < 32; ++ct) {
        int row = ct * 16 + lm;
        v8s cb0 = *(const v8s*)&L[toff(12288, row, quad * 8, 8)];
        v8s cb1 = *(const v8s*)&L[toff(12288, row, 32 + quad * 8, 8)];
        float ev = LF[row];
        v4f seed = {ev, ev, ev, ev};
#pragma unroll
        for (int t = 0; t < 2; ++t) {
          v4f acc = __builtin_amdgcn_mfma_f32_16x16x32_bf16(za[t][0], cb0, seed, 0, 0, 0);
          acc = __builtin_amdgcn_mfma_f32_16x16x32_bf16(za[t][1], cb1, acc, 0, 0, 0);
#pragma unroll
          for (int r = 0; r < 4; ++r)
            if (acc[r] < bd[t][r]) { bd[t][r] = acc[r]; bc[t][r] = row; }
        }
      }
    }

    int idxv[2];
#pragma unroll
    for (int t = 0; t < 2; ++t) {
      float z2p[4];
#pragma unroll
      for (int r = 0; r < 4; ++r)
        z2p[r] = accz[t][0][r] * accz[t][0][r] + accz[t][1][r] * accz[t][1][r]
               + accz[t][2][r] * accz[t][2][r] + accz[t][3][r] * accz[t][3][r];
#pragma unroll
      for (int off = 1; off < 16; off <<= 1) {
#pragma unroll
        for (int r = 0; r < 4; ++r) {
          float od = __shfl_xor(bd[t][r], off, 64);
          int   oc = __shfl_xor(bc[t][r], off, 64);
          if (od < bd[t][r] || (od == bd[t][r] && oc < bc[t][r])) { bd[t][r] = od; bc[t][r] = oc; }
          z2p[r] += __shfl_xor(z2p[r], off, 64);
        }
      }
      if (lm == 0) {
#pragma unroll
        for (int r = 0; r < 4; ++r) vqacc += z2p[r] + bd[t][r];   // ||z-q||^2
      }
      int i0 = __shfl(bc[t][0], (lm >> 2) << 4, 64);
      int i1 = __shfl(bc[t][1], (lm >> 2) << 4, 64);
      int i2 = __shfl(bc[t][2], (lm >> 2) << 4, 64);
      int i3 = __shfl(bc[t][3], (lm >> 2) << 4, 64);
      int sel = lm & 3;
      idxv[t] = sel == 0 ? i0 : sel == 1 ? i1 : sel == 2 ? i2 : i3;
    }

    // ---- stage 5: HD = relu(Q @ DW1 + db1), Q gathered from LDS codebook ----
    {
      v8s qa[2][2];
#pragma unroll
      for (int t = 0; t < 2; ++t) {
        qa[t][0] = *(const v8s*)&L[toff(12288, idxv[t], quad * 8, 8)];
        qa[t][1] = *(const v8s*)&L[toff(12288, idxv[t], 32 + quad * 8, 8)];
      }
#pragma unroll
      for (int nt = 0; nt < 8; ++nt) {
        int row = nt * 16 + lm;
        v8s b0 = *(const v8s*)&L[toff(45056, row, quad * 8, 8)];
        v8s b1 = *(const v8s*)&L[toff(45056, row, 32 + quad * 8, 8)];
        float bv = LF[704 + row];
        v4f seed = {bv, bv, bv, bv};
#pragma unroll
        for (int t = 0; t < 2; ++t) {
          v4f acc = __builtin_amdgcn_mfma_f32_16x16x32_bf16(qa[t][0], b0, seed, 0, 0, 0);
          acc = __builtin_amdgcn_mfma_f32_16x16x32_bf16(qa[t][1], b1, acc, 0, 0, 0);
#pragma unroll
          for (int r = 0; r < 4; ++r)
            Act[t][swz(quad * 4 + r, row)] = f2bf(fmaxf(acc[r], 0.f));
        }
      }
    }

    // ---- stage 6: R = HD @ DW2 + db2; store + recon loss ----
    {
      v8s hd[2][4];
#pragma unroll
      for (int t = 0; t < 2; ++t)
#pragma unroll
        for (int ks = 0; ks < 4; ++ks)
          hd[t][ks] = *(const v8s*)&Act[t][swz(lm, ks * 32 + quad * 8)];
      v4f acc[2][2];
#pragma unroll
      for (int nt = 0; nt < 2; ++nt) {
        int row = nt * 16 + lm;
        float bv = LF[832 + row];
#pragma unroll
        for (int t = 0; t < 2; ++t) acc[t][nt] = (v4f){bv, bv, bv, bv};
#pragma unroll
        for (int ks = 0; ks < 4; ++ks) {
          v8s frag = *(const v8s*)&L[toff(53248, row, ks * 32 + quad * 8, 16)];
#pragma unroll
          for (int t = 0; t < 2; ++t)
            acc[t][nt] = __builtin_amdgcn_mfma_f32_16x16x32_bf16(hd[t][ks], frag, acc[t][nt], 0, 0, 0);
        }
      }
#pragma unroll
      for (int t = 0; t < 2; ++t)
#pragma unroll
        for (int nt = 0; nt < 2; ++nt) {
          int n = nt * 16 + lm;
          bool valid = (n < IN_DIM);
#pragma unroll
          for (int r = 0; r < 4; ++r) {
            float rec = acc[t][nt][r];
            if (valid) {
              size_t o = (size_t)(rt0 + t * 16 + quad * 4 + r) * IN_DIM + n;
              out[o] = rec;
              float dv = rec - x[o];
              racc += dv * dv;
            }
          }
        }
    }
  }

  // ---- per-wave butterfly, per-wave partial store (no atomics, no barrier) ----
#pragma unroll
  for (int off = 1; off < 64; off <<= 1) {
    racc  += __shfl_xor(racc, off, 64);
    vqacc += __shfl_xor(vqacc, off, 64);
  }
  if (lane == 0) {
    size_t w = (size_t)blockIdx.x * 4 + wave;
    partials[w * 2]     = racc;
    partials[w * 2 + 1] = vqacc;
  }
}

// ---------------- finalize: reduce per-wave partials, write scalars ----------------
__global__ __launch_bounds__(256) void vq_fin(const float* __restrict__ partials,
                                              float* __restrict__ out) {
  float r = 0.f, v = 0.f;
  for (int i = threadIdx.x; i < NWAVE; i += 256) {
    r += partials[2 * i];
    v += partials[2 * i + 1];
  }
#pragma unroll
  for (int off = 1; off < 64; off <<= 1) {
    r += __shfl_xor(r, off, 64);
    v += __shfl_xor(v, off, 64);
  }
  __shared__ float s[4][2];
  int w = threadIdx.x >> 6;
  if ((threadIdx.x & 63) == 0) { s[w][0] = r; s[w][1] = v; }
  __syncthreads();
  if (threadIdx.x == 0) {
    float R = s[0][0] + s[1][0] + s[2][0] + s[3][0];
    float V = s[0][1] + s[1][1] + s[2][1] + s[3][1];
    out[7340032] = R * (1.0f / 7340032.0f);          // recon_loss = S / (B*28)
    out[7340033] = V * (1.25f / 16777216.0f);        // vq_loss = 1.25 * S / (B*64)
  }
}

extern "C" void kernel_launch(void* const* d_in, const int* in_sizes, int n_in,
                              void* d_out, int out_size, void* d_ws, size_t ws_size,
                              hipStream_t stream) {
  const float* x   = (const float*)d_in[0];
  const float* ew1 = (const float*)d_in[1];
  const float* eb1 = (const float*)d_in[2];
  const float* ew2 = (const float*)d_in[3];
  const float* eb2 = (const float*)d_in[4];
  const float* cb  = (const float*)d_in[5];
  const float* dw1 = (const float*)d_in[6];
  const float* db1 = (const float*)d_in[7];
  const float* dw2 = (const float*)d_in[8];
  const float* db2 = (const float*)d_in[9];

  char* ws = (char*)d_ws;
  unsigned short* blob = (unsigned short*)(ws + 0);   // 118144 B
  float* partials = (float*)(ws + 118272);            // 32768 B

  float* out = (float*)d_out;

  // allow >64 KB dynamic LDS (gfx950 workgroup max is 160 KB)
  static int attr_done = 0;
  (void)attr_done;
  (void)hipFuncSetAttribute((const void*)vq_main,
                            hipFuncAttributeMaxDynamicSharedMemorySize, LDS_BYTES);

  vq_prep<<<228, 256, 0, stream>>>(ew1, eb1, ew2, eb2, cb, dw1, db1, dw2, db2, blob);
  vq_main<<<NBLK, 256, LDS_BYTES, stream>>>(x, blob, out, partials);
  vq_fin<<<1, 256, 0, stream>>>(partials, out);
}

// Round 6
// 177.259 us; speedup vs baseline: 1.9273x; 1.1681x over previous
//
#include <hip/hip_runtime.h>

#define BATCH   262144
#define IN_DIM  28
#define HID     128
#define LAT     64
#define NCODES  512
#define NBLK    1024            // 256 rows per block (8 waves x 32 rows)
#define NWAVE   (NBLK * 8)

#define BLOB_SHORTS 57344       // bf16 table region (shorts)
#define BLOB_F32    864         // fp32 region (e2 + biases)
#define BLOB_BYTES  (BLOB_SHORTS * 2 + BLOB_F32 * 4)   // 118144
#define ACT_BASE    (BLOB_BYTES / 2)                    // short offset 59072
#define LDS_BYTES   (BLOB_BYTES + 8 * 2048 * 2)         // 150912

typedef short v8s __attribute__((ext_vector_type(8)));
typedef float v4f __attribute__((ext_vector_type(4)));

__device__ __forceinline__ unsigned short f2bf(float f) {
  unsigned u = __float_as_uint(f);
  u += 0x7fffu + ((u >> 16) & 1u);   // round-to-nearest-even
  return (unsigned short)(u >> 16);
}

// Bank-swizzled table offset (in shorts): row-major with 16B col-blocks
// XOR-permuted by row so same-col-block reads across lanes hit distinct banks.
__device__ __forceinline__ int toff(int base, int row, int col, int SB) {
  return base + row * (SB * 8) + ((((col >> 3) ^ row) & (SB - 1)) << 3) + (col & 7);
}

// XOR-swizzled 16-row activation tile (per wave), offsets in shorts.
__device__ __forceinline__ int swz(int row, int col) {
  int g = col >> 3;
  return (g * 16 + ((row ^ g) & 15)) * 8 + (col & 7);
}

// Blob layout (short offsets):
//   lw1  @0      [128 n][32 k]  SB=4   enc_w1^T (k>=28 zero)
//   lw2  @4096   [64 n][128 k]  SB=16  enc_w2^T
//   lcb  @12288  [512 c][64 d]  SB=8   bf16 codebook
//   ld1  @45056  [128 n][64 k]  SB=8   dec_w1^T
//   ld2  @53248  [32 n][128 k]  SB=16  dec_w2^T (n>=28 zero)
// fp32 @ byte 114688: e2[512], b1[128], b2[64], db1[128], db2[32 pad0]
__global__ __launch_bounds__(256) void vq_prep(
    const float* __restrict__ ew1, const float* __restrict__ eb1,
    const float* __restrict__ ew2, const float* __restrict__ eb2,
    const float* __restrict__ cb,  const float* __restrict__ dw1,
    const float* __restrict__ db1, const float* __restrict__ dw2,
    const float* __restrict__ db2,
    unsigned short* __restrict__ blob) {
  int i = blockIdx.x * 256 + threadIdx.x;
  float* fb = (float*)(blob + BLOB_SHORTS);
  if (i < 4096) {                       // lw1
    int row = i >> 5, col = i & 31;
    float v = (col < IN_DIM) ? ew1[col * HID + row] : 0.f;
    blob[toff(0, row, col, 4)] = f2bf(v);
  } else if (i < 12288) {               // lw2
    int j = i - 4096; int row = j >> 7, col = j & 127;
    blob[toff(4096, row, col, 16)] = f2bf(ew2[col * LAT + row]);
  } else if (i < 45056) {               // lcb
    int j = i - 12288; int row = j >> 6, col = j & 63;
    blob[toff(12288, row, col, 8)] = f2bf(cb[j]);
  } else if (i < 53248) {               // ld1
    int j = i - 45056; int row = j >> 6, col = j & 63;
    blob[toff(45056, row, col, 8)] = f2bf(dw1[col * HID + row]);
  } else if (i < 57344) {               // ld2
    int j = i - 53248; int row = j >> 7, col = j & 127;
    float v = (row < IN_DIM) ? dw2[col * IN_DIM + row] : 0.f;
    blob[toff(53248, row, col, 16)] = f2bf(v);
  } else if (i < 57344 + 512) {         // e2
    int c = i - 57344;
    float s = 0.f;
    for (int d = 0; d < LAT; ++d) { float v = cb[c * LAT + d]; s += v * v; }
    fb[c] = s;
  } else if (i < 57344 + 640) {
    fb[i - 57344] = eb1[i - 57344 - 512];
  } else if (i < 57344 + 704) {
    fb[i - 57344] = eb2[i - 57344 - 640];
  } else if (i < 57344 + 832) {
    fb[i - 57344] = db1[i - 57344 - 704];
  } else if (i < 57344 + 864) {
    int k = i - 57344 - 832;
    fb[i - 57344] = (k < IN_DIM) ? db2[k] : 0.f;
  }
}

// ---------------- fused main kernel ----------------
// Tables staged once per block into LDS (round-5 win). Round-6 change: 8
// waves per block (512 threads) at the SAME LDS footprint (one 4 KB act tile
// per wave, R=1) -> 2 waves/SIMD instead of 1, hiding the serial-chain
// latency that left the SIMDs 70% idle at 4 waves/CU.
__global__ __launch_bounds__(512, 2) void vq_main(
    const float* __restrict__ x,
    const unsigned short* __restrict__ blob,
    float* __restrict__ out, float* __restrict__ partials) {

  extern __shared__ __align__(16) char smem[];
  unsigned short* L  = (unsigned short*)smem;
  float*          LF = (float*)(smem + BLOB_SHORTS * 2);

  const int tid  = threadIdx.x;
  const int wave = tid >> 6;
  const int lane = tid & 63;
  const int quad = lane >> 4;
  const int lm   = lane & 15;

  // ---- stage tables into LDS (one-time) ----
  {
    const float4* src = (const float4*)blob;
    float4* dst = (float4*)smem;
#pragma unroll
    for (int it = 0; it < 15; ++it) {
      int idx = it * 512 + tid;
      if (idx < BLOB_BYTES / 16) dst[idx] = src[idx];
    }
  }
  __syncthreads();

  unsigned short* A = L + ACT_BASE + wave * 2048;

  float racc = 0.f, vqacc = 0.f;
  const int rbase = blockIdx.x * 256 + wave * 32;

#pragma unroll
  for (int it = 0; it < 2; ++it) {
    const int r0 = rbase + it * 16;

    // ---- stage 1: H = relu(X @ W1 + b1) ----
    v8s a1;
    {
      const float* xp = x + (size_t)(r0 + lm) * IN_DIM + quad * 8;
      float4 v0 = *(const float4*)xp;
      float4 v1;
      if (quad == 3) { v1.x = 0.f; v1.y = 0.f; v1.z = 0.f; v1.w = 0.f; }
      else           { v1 = *(const float4*)(xp + 4); }
      a1[0] = (short)f2bf(v0.x); a1[1] = (short)f2bf(v0.y);
      a1[2] = (short)f2bf(v0.z); a1[3] = (short)f2bf(v0.w);
      a1[4] = (short)f2bf(v1.x); a1[5] = (short)f2bf(v1.y);
      a1[6] = (short)f2bf(v1.z); a1[7] = (short)f2bf(v1.w);
    }
#pragma unroll
    for (int nt = 0; nt < 8; ++nt) {
      int row = nt * 16 + lm;
      v8s frag = *(const v8s*)&L[toff(0, row, quad * 8, 4)];
      float bv = LF[512 + row];
      v4f seed = {bv, bv, bv, bv};
      v4f acc = __builtin_amdgcn_mfma_f32_16x16x32_bf16(a1, frag, seed, 0, 0, 0);
#pragma unroll
      for (int r = 0; r < 4; ++r)
        A[swz(quad * 4 + r, row)] = f2bf(fmaxf(acc[r], 0.f));
    }

    // ---- stage 2: Z = H @ W2 + b2 (z fp32 in regs) ----
    v4f accz[4];
    {
      v8s ha[4];
#pragma unroll
      for (int ks = 0; ks < 4; ++ks)
        ha[ks] = *(const v8s*)&A[swz(lm, ks * 32 + quad * 8)];
#pragma unroll
      for (int nt = 0; nt < 4; ++nt) {
        int row = nt * 16 + lm;
        float bv = LF[640 + row];
        accz[nt] = (v4f){bv, bv, bv, bv};
#pragma unroll
        for (int ks = 0; ks < 4; ++ks) {
          v8s frag = *(const v8s*)&L[toff(4096, row, ks * 32 + quad * 8, 16)];
          accz[nt] = __builtin_amdgcn_mfma_f32_16x16x32_bf16(ha[ks], frag, accz[nt], 0, 0, 0);
        }
      }
      // write zm2 = bf16(-2*z) (exact x2) as the argmin MFMA A-operand
#pragma unroll
      for (int nt = 0; nt < 4; ++nt)
#pragma unroll
        for (int r = 0; r < 4; ++r)
          A[swz(quad * 4 + r, nt * 16 + lm)] = f2bf(-2.f * accz[nt][r]);
    }

    // ---- argmin: dist = e2 + (-2z).e via MFMA, e2 in acc seed ----
    float bd[4]; int bc[4];
#pragma unroll
    for (int r = 0; r < 4; ++r) { bd[r] = 3.4e38f; bc[r] = 0x7fffffff; }
    {
      v8s za0 = *(const v8s*)&A[swz(lm, quad * 8)];
      v8s za1 = *(const v8s*)&A[swz(lm, 32 + quad * 8)];
#pragma unroll 4
      for (int ct = 0; ct < 32; ++ct) {
        int row = ct * 16 + lm;
        v8s cb0 = *(const v8s*)&L[toff(12288, row, quad * 8, 8)];
        v8s cb1 = *(const v8s*)&L[toff(12288, row, 32 + quad * 8, 8)];
        float ev = LF[row];
        v4f seed = {ev, ev, ev, ev};
        v4f acc = __builtin_amdgcn_mfma_f32_16x16x32_bf16(za0, cb0, seed, 0, 0, 0);
        acc = __builtin_amdgcn_mfma_f32_16x16x32_bf16(za1, cb1, acc, 0, 0, 0);
#pragma unroll
        for (int r = 0; r < 4; ++r)
          if (acc[r] < bd[r]) { bd[r] = acc[r]; bc[r] = row; }   // ascending -> lowest idx on tie
      }
    }

    // z^2 partial + 16-lane reduce (argmin w/ tie-break, z2 sum)
    float z2p[4];
#pragma unroll
    for (int r = 0; r < 4; ++r)
      z2p[r] = accz[0][r] * accz[0][r] + accz[1][r] * accz[1][r]
             + accz[2][r] * accz[2][r] + accz[3][r] * accz[3][r];
#pragma unroll
    for (int off = 1; off < 16; off <<= 1) {
#pragma unroll
      for (int r = 0; r < 4; ++r) {
        float od = __shfl_xor(bd[r], off, 64);
        int   oc = __shfl_xor(bc[r], off, 64);
        if (od < bd[r] || (od == bd[r] && oc < bc[r])) { bd[r] = od; bc[r] = oc; }
        z2p[r] += __shfl_xor(z2p[r], off, 64);
      }
    }
    if (lm == 0) {
#pragma unroll
      for (int r = 0; r < 4; ++r) vqacc += z2p[r] + bd[r];   // ||z-q||^2
    }
    int i0 = __shfl(bc[0], (lm >> 2) << 4, 64);
    int i1 = __shfl(bc[1], (lm >> 2) << 4, 64);
    int i2 = __shfl(bc[2], (lm >> 2) << 4, 64);
    int i3 = __shfl(bc[3], (lm >> 2) << 4, 64);
    int sel = lm & 3;
    int idxv = sel == 0 ? i0 : sel == 1 ? i1 : sel == 2 ? i2 : i3;

    // ---- stage 5: HD = relu(Q @ DW1 + db1), Q gathered from LDS codebook ----
    {
      v8s qa0 = *(const v8s*)&L[toff(12288, idxv, quad * 8, 8)];
      v8s qa1 = *(const v8s*)&L[toff(12288, idxv, 32 + quad * 8, 8)];
#pragma unroll
      for (int nt = 0; nt < 8; ++nt) {
        int row = nt * 16 + lm;
        v8s b0 = *(const v8s*)&L[toff(45056, row, quad * 8, 8)];
        v8s b1 = *(const v8s*)&L[toff(45056, row, 32 + quad * 8, 8)];
        float bv = LF[704 + row];
        v4f seed = {bv, bv, bv, bv};
        v4f acc = __builtin_amdgcn_mfma_f32_16x16x32_bf16(qa0, b0, seed, 0, 0, 0);
        acc = __builtin_amdgcn_mfma_f32_16x16x32_bf16(qa1, b1, acc, 0, 0, 0);
#pragma unroll
        for (int r = 0; r < 4; ++r)
          A[swz(quad * 4 + r, row)] = f2bf(fmaxf(acc[r], 0.f));
      }
    }

    // ---- stage 6: R = HD @ DW2 + db2; store + recon loss ----
    {
      v8s hd[4];
#pragma unroll
      for (int ks = 0; ks < 4; ++ks)
        hd[ks] = *(const v8s*)&A[swz(lm, ks * 32 + quad * 8)];
      v4f acc[2];
#pragma unroll
      for (int nt = 0; nt < 2; ++nt) {
        int row = nt * 16 + lm;
        float bv = LF[832 + row];
        acc[nt] = (v4f){bv, bv, bv, bv};
#pragma unroll
        for (int ks = 0; ks < 4; ++ks) {
          v8s frag = *(const v8s*)&L[toff(53248, row, ks * 32 + quad * 8, 16)];
          acc[nt] = __builtin_amdgcn_mfma_f32_16x16x32_bf16(hd[ks], frag, acc[nt], 0, 0, 0);
        }
      }
#pragma unroll
      for (int nt = 0; nt < 2; ++nt) {
        int n = nt * 16 + lm;
        bool valid = (n < IN_DIM);
#pragma unroll
        for (int r = 0; r < 4; ++r) {
          float rec = acc[nt][r];
          if (valid) {
            size_t o = (size_t)(r0 + quad * 4 + r) * IN_DIM + n;
            out[o] = rec;
            float dv = rec - x[o];
            racc += dv * dv;
          }
        }
      }
    }
  }

  // ---- per-wave butterfly, per-wave partial store (no atomics, no barrier) ----
#pragma unroll
  for (int off = 1; off < 64; off <<= 1) {
    racc  += __shfl_xor(racc, off, 64);
    vqacc += __shfl_xor(vqacc, off, 64);
  }
  if (lane == 0) {
    size_t w = (size_t)blockIdx.x * 8 + wave;
    partials[w * 2]     = racc;
    partials[w * 2 + 1] = vqacc;
  }
}

// ---------------- finalize: reduce per-wave partials, write scalars ----------------
__global__ __launch_bounds__(256) void vq_fin(const float* __restrict__ partials,
                                              float* __restrict__ out) {
  float r = 0.f, v = 0.f;
  for (int i = threadIdx.x; i < NWAVE; i += 256) {
    r += partials[2 * i];
    v += partials[2 * i + 1];
  }
#pragma unroll
  for (int off = 1; off < 64; off <<= 1) {
    r += __shfl_xor(r, off, 64);
    v += __shfl_xor(v, off, 64);
  }
  __shared__ float s[4][2];
  int w = threadIdx.x >> 6;
  if ((threadIdx.x & 63) == 0) { s[w][0] = r; s[w][1] = v; }
  __syncthreads();
  if (threadIdx.x == 0) {
    float R = s[0][0] + s[1][0] + s[2][0] + s[3][0];
    float V = s[0][1] + s[1][1] + s[2][1] + s[3][1];
    out[7340032] = R * (1.0f / 7340032.0f);          // recon_loss = S / (B*28)
    out[7340033] = V * (1.25f / 16777216.0f);        // vq_loss = 1.25 * S / (B*64)
  }
}

extern "C" void kernel_launch(void* const* d_in, const int* in_sizes, int n_in,
                              void* d_out, int out_size, void* d_ws, size_t ws_size,
                              hipStream_t stream) {
  const float* x   = (const float*)d_in[0];
  const float* ew1 = (const float*)d_in[1];
  const float* eb1 = (const float*)d_in[2];
  const float* ew2 = (const float*)d_in[3];
  const float* eb2 = (const float*)d_in[4];
  const float* cb  = (const float*)d_in[5];
  const float* dw1 = (const float*)d_in[6];
  const float* db1 = (const float*)d_in[7];
  const float* dw2 = (const float*)d_in[8];
  const float* db2 = (const float*)d_in[9];

  char* ws = (char*)d_ws;
  unsigned short* blob = (unsigned short*)(ws + 0);   // 118144 B
  float* partials = (float*)(ws + 118272);            // 65536 B (8192*2 f32)

  float* out = (float*)d_out;

  // allow >64 KB dynamic LDS (gfx950 workgroup max is 160 KB)
  (void)hipFuncSetAttribute((const void*)vq_main,
                            hipFuncAttributeMaxDynamicSharedMemorySize, LDS_BYTES);

  vq_prep<<<228, 256, 0, stream>>>(ew1, eb1, ew2, eb2, cb, dw1, db1, dw2, db2, blob);
  vq_main<<<NBLK, 512, LDS_BYTES, stream>>>(x, blob, out, partials);
  vq_fin<<<1, 256, 0, stream>>>(partials, out);
}